// Round 3
// baseline (524.383 us; speedup 1.0000x reference)
//
#include <hip/hip_runtime.h>
#include <hip/hip_bf16.h>
#include <math.h>

typedef unsigned short u16;
typedef float f32x4 __attribute__((ext_vector_type(4)));
typedef __bf16 bf16x8 __attribute__((ext_vector_type(8)));

__device__ __forceinline__ float bf2f(u16 u) {
    union { float f; unsigned int i; } v; v.i = ((unsigned int)u) << 16; return v.f;
}
__device__ __forceinline__ u16 f2bf(float f) {
    union { float f; unsigned int i; } v; v.f = f;
    unsigned int x = v.i;
    return (u16)((x + 0x7FFFu + ((x >> 16) & 1u)) >> 16);
}

// ---------------- K1: NCHW f32 -> NHWC bf16 transpose ----------------
// grid (49, 4, 16), block 256
__global__ __launch_bounds__(256) void k_transpose(const float* __restrict__ x, u16* __restrict__ xh) {
    __shared__ __align__(16) u16 tile[64][72];
    const int t = threadIdx.x;
    const int hw0 = blockIdx.x * 64;
    const int c0  = blockIdx.y * 64;
    const int b   = blockIdx.z;
    // load: 64 c-rows x 64 hw-cols of f32, convert to bf16 in LDS
    const int cl = t >> 2, wl = (t & 3) * 16;
    {
        int c = c0 + cl;
        const float* src = x + (size_t)(b * 256 + c) * 3136 + hw0 + wl;
        for (int q = 0; q < 4; q++) {
            float4 v = *(const float4*)(src + q * 4);
            u16* dst = &tile[cl][wl + q * 4];
            dst[0] = f2bf(v.x); dst[1] = f2bf(v.y); dst[2] = f2bf(v.z); dst[3] = f2bf(v.w);
        }
    }
    __syncthreads();
    const int hl = t >> 3, cl2 = (t & 7) * 8;
    for (int i = 0; i < 2; i++) {
        int hw = hl + i * 32;
        alignas(16) u16 tmp[8];
        for (int j = 0; j < 8; j++) tmp[j] = tile[cl2 + j][hw];
        u16* dst = xh + (size_t)(b * 3136 + hw0 + hw) * 256 + c0 + cl2;
        *(int4*)dst = *(int4*)tmp;
    }
}

// ---------------- K2/K5: LayerNorm over C=256 per position (bf16 in/out, f32 params) ----------------
// grid (12544), block 256 (4 waves, 1 position/wave)
__global__ __launch_bounds__(256) void k_ln(const u16* __restrict__ in, u16* __restrict__ out,
                                            const float* __restrict__ g, const float* __restrict__ bta) {
    const int wave = threadIdx.x >> 6, lane = threadIdx.x & 63;
    const int p = blockIdx.x * 4 + wave;
    const u16* row = in + (size_t)p * 256 + lane * 4;
    ushort4 v = *(const ushort4*)row;
    float f0 = bf2f(v.x), f1 = bf2f(v.y), f2 = bf2f(v.z), f3 = bf2f(v.w);
    float s = f0 + f1 + f2 + f3;
    float sq = f0 * f0 + f1 * f1 + f2 * f2 + f3 * f3;
    for (int o = 32; o >= 1; o >>= 1) { s += __shfl_xor(s, o, 64); sq += __shfl_xor(sq, o, 64); }
    float mu = s * (1.f / 256.f);
    float var = sq * (1.f / 256.f) - mu * mu;
    float inv = rsqrtf(var + 1e-5f);
    float4 gv = *(const float4*)(g + lane * 4);
    float4 bv = *(const float4*)(bta + lane * 4);
    ushort4 o4;
    o4.x = f2bf((f0 - mu) * inv * gv.x + bv.x);
    o4.y = f2bf((f1 - mu) * inv * gv.y + bv.y);
    o4.z = f2bf((f2 - mu) * inv * gv.z + bv.z);
    o4.w = f2bf((f3 - mu) * inv * gv.w + bv.w);
    *(ushort4*)(out + (size_t)p * 256 + lane * 4) = o4;
}

// ---------------- GEMM: C[M,N] = A[M,K] @ B[N,K]^T (+epilogues) ----------------
// A: bf16 (ours). B: f32 weights (converted to bf16 while staging). bias/gamma: f32.
// MODE 0: qkv = xn @ [wq;wkv]^T + [bq;bkv]   (K=256, N=768, ldout=768)
// MODE 1: hmid = gelu(xn @ w1^T + b1)        (K=256, N=1024, ldout=1024)
// MODE 2: out_nchw(f32) = x2 + gamma2*(hmid @ w2^T + b2)  (K=1024, N=256)
template <int MODE>
__global__ __launch_bounds__(256) void k_gemm(
    const u16* __restrict__ A,
    const float* __restrict__ B0, const float* __restrict__ B1,
    const float* __restrict__ bias0, const float* __restrict__ bias1,
    u16* __restrict__ out,
    const u16* __restrict__ x2, const float* __restrict__ g2v, float* __restrict__ outT) {
    constexpr int K = (MODE == 2) ? 1024 : 256;
    constexpr int NSPLIT = (MODE == 0) ? 256 : (1 << 30);
    constexpr int LDOUT = (MODE == 0) ? 768 : 1024;

    __shared__ __align__(16) u16 As[128 * 32];
    __shared__ __align__(16) u16 Bs[128 * 32];

    const int t = threadIdx.x;
    const int bm = blockIdx.x, bn = blockIdx.y;
    const int wave = t >> 6, lane = t & 63;
    const int wm = (wave >> 1) * 64, wn = (wave & 1) * 64;
    const int ln = lane & 15, quad = lane >> 4;

    f32x4 vzero = {0.f, 0.f, 0.f, 0.f};
    f32x4 acc[4][4];
    for (int i = 0; i < 4; i++) for (int j = 0; j < 4; j++) acc[i][j] = vzero;

    const int srow = t >> 2;
    const int scol = (t & 3) * 8;

    for (int k0 = 0; k0 < K; k0 += 32) {
        for (int i = 0; i < 2; i++) {
            int r = srow + i * 64;
            *(int4*)&As[r * 32 + scol] = *(const int4*)(A + (size_t)(bm * 128 + r) * K + k0 + scol);
        }
        for (int i = 0; i < 2; i++) {
            int r = srow + i * 64;
            int gn = bn * 128 + r;
            const float* bp = (gn < NSPLIT) ? (B0 + (size_t)gn * K) : (B1 + (size_t)(gn - NSPLIT) * K);
            float4 v0 = *(const float4*)(bp + k0 + scol);
            float4 v1 = *(const float4*)(bp + k0 + scol + 4);
            alignas(16) u16 tmp[8];
            tmp[0] = f2bf(v0.x); tmp[1] = f2bf(v0.y); tmp[2] = f2bf(v0.z); tmp[3] = f2bf(v0.w);
            tmp[4] = f2bf(v1.x); tmp[5] = f2bf(v1.y); tmp[6] = f2bf(v1.z); tmp[7] = f2bf(v1.w);
            *(int4*)&Bs[r * 32 + scol] = *(int4*)tmp;
        }
        __syncthreads();
        bf16x8 af[4], bfr[4];
        for (int mt = 0; mt < 4; mt++) af[mt] = *(const bf16x8*)&As[(wm + mt * 16 + ln) * 32 + quad * 8];
        for (int nt = 0; nt < 4; nt++) bfr[nt] = *(const bf16x8*)&Bs[(wn + nt * 16 + ln) * 32 + quad * 8];
        for (int mt = 0; mt < 4; mt++)
            for (int nt = 0; nt < 4; nt++)
                acc[mt][nt] = __builtin_amdgcn_mfma_f32_16x16x32_bf16(af[mt], bfr[nt], acc[mt][nt], 0, 0, 0);
        __syncthreads();
    }

    for (int nt = 0; nt < 4; nt++) {
        int gn = bn * 128 + wn + nt * 16 + ln;
        float bias;
        if (MODE == 0) bias = (gn < NSPLIT) ? bias0[gn] : bias1[gn - NSPLIT];
        else bias = bias0[gn];
        float g2 = (MODE == 2) ? g2v[gn] : 0.f;
        for (int mt = 0; mt < 4; mt++) {
            int gm0 = bm * 128 + wm + mt * 16 + quad * 4;
            for (int r = 0; r < 4; r++) {
                int gm = gm0 + r;
                float v = acc[mt][nt][r] + bias;
                if (MODE == 1) v = 0.5f * v * (1.f + erff(v * 0.70710678118654752f));
                if (MODE == 2) {
                    int b = gm / 3136, hw = gm - b * 3136;
                    float res = bf2f(x2[(size_t)gm * 256 + gn]) + g2 * v;
                    outT[(size_t)(b * 256 + gn) * 3136 + hw] = res;   // f32 output!
                } else {
                    out[(size_t)gm * LDOUT + gn] = f2bf(v);
                }
            }
        }
    }
}

// ---------------- K4: halo attention + LayerScale residual ----------------
// grid (49, 8, 16), block 256 (4 waves, wave = 16-query m-tile)
__global__ __launch_bounds__(256) void k_attn(
    const u16* __restrict__ qkv, const float* __restrict__ bias,
    const u16* __restrict__ xh, const float* __restrict__ gamma1,
    u16* __restrict__ x2) {
    __shared__ __align__(16) u16 Kl[208 * 40];      // K[k_pos][d], padded stride
    __shared__ __align__(16) u16 Vt[32 * 232];      // V^T[d][k_pos]
    __shared__ __align__(16) u16 Pl[4][16 * 232];   // per-wave P[q][k_pos]

    const int t = threadIdx.x;
    const int blk = blockIdx.x, head = blockIdx.y, b = blockIdx.z;
    const int bh = blk / 7, bw = blk - bh * 7;
    const int wave = t >> 6, lane = t & 63;
    const int ln = lane & 15, quad = lane >> 4;

    {
        int4 z = {0, 0, 0, 0};
        for (int i = t; i < (32 * 232) / 8; i += 256) ((int4*)Vt)[i] = z;
        for (int i = t; i < (4 * 16 * 232) / 8; i += 256) ((int4*)&Pl[0][0])[i] = z;
    }
    __syncthreads();

    // gather K window and V^T window (zero-padded halo; reference pads projected kv with zeros,
    // so OOB keys still get score = 0 + bias and zero V)
    for (int cid = t; cid < 208 * 8; cid += 256) {
        int pos = cid >> 3, part = cid & 7;
        int i = pos / 14, j = pos - i * 14;
        int gh = bh * 8 - 3 + i, gw = bw * 8 - 3 + j;
        bool valid = (pos < 196) && ((unsigned)gh < 56u) && ((unsigned)gw < 56u);
        int d0 = (part & 3) * 8;
        int4 v = {0, 0, 0, 0};
        if (valid) {
            size_t p = (size_t)(b * 56 + gh) * 56 + gw;
            v = *(const int4*)(qkv + p * 768 + 256 + head * 64 + ((part & 4) ? 32 : 0) + d0);
        }
        if (!(part & 4)) {
            *(int4*)&Kl[pos * 40 + d0] = v;
        } else {
            alignas(16) u16 tmp[8];
            *(int4*)tmp = v;
            for (int jj = 0; jj < 8; jj++) Vt[(d0 + jj) * 232 + pos] = tmp[jj];
        }
    }
    __syncthreads();

    // Q fragment straight from global: A[m=ln][k=quad*8+j]
    const int qrow = wave * 16 + ln;
    const int qh = bh * 8 + (qrow >> 3), qw = bw * 8 + (qrow & 7);
    const size_t qp = (size_t)(b * 56 + qh) * 56 + qw;
    bf16x8 qf = *(const bf16x8*)(qkv + qp * 768 + head * 32 + quad * 8);

    f32x4 vzero = {0.f, 0.f, 0.f, 0.f};
    float sv[13][4];
    float mx[4] = {-1e30f, -1e30f, -1e30f, -1e30f};
    const float scale = 0.17677669529663687f;  // 1/sqrt(32)
    for (int nt = 0; nt < 13; nt++) {
        bf16x8 kf = *(const bf16x8*)&Kl[(nt * 16 + ln) * 40 + quad * 8];
        f32x4 s = __builtin_amdgcn_mfma_f32_16x16x32_bf16(qf, kf, vzero, 0, 0, 0);
        int kk = nt * 16 + ln;
        bool kvalid = kk < 196;
        for (int r = 0; r < 4; r++) {
            int qq = wave * 16 + quad * 4 + r;
            float val = kvalid ? (s[r] * scale + bias[(size_t)(head * 64 + qq) * 196 + kk]) : -1e30f;
            sv[nt][r] = val;
            mx[r] = fmaxf(mx[r], val);
        }
    }
    for (int o = 1; o < 16; o <<= 1)
        for (int r = 0; r < 4; r++) mx[r] = fmaxf(mx[r], __shfl_xor(mx[r], o, 16));
    float sum[4] = {0.f, 0.f, 0.f, 0.f};
    for (int nt = 0; nt < 13; nt++)
        for (int r = 0; r < 4; r++) {
            float e = __expf(sv[nt][r] - mx[r]);
            sv[nt][r] = e;
            sum[r] += e;
        }
    for (int o = 1; o < 16; o <<= 1)
        for (int r = 0; r < 4; r++) sum[r] += __shfl_xor(sum[r], o, 16);
    float rinv[4];
    for (int r = 0; r < 4; r++) rinv[r] = 1.f / sum[r];

    // P (D-layout) -> LDS -> A-layout
    u16* plw = &Pl[wave][0];
    for (int nt = 0; nt < 13; nt++)
        for (int r = 0; r < 4; r++)
            plw[(quad * 4 + r) * 232 + nt * 16 + ln] = f2bf(sv[nt][r]);
    __syncthreads();

    f32x4 o_acc[2];
    o_acc[0] = vzero; o_acc[1] = vzero;
    for (int kc = 0; kc < 7; kc++) {
        bf16x8 pf = *(const bf16x8*)&plw[ln * 232 + kc * 32 + quad * 8];
        for (int n2 = 0; n2 < 2; n2++) {
            bf16x8 vf = *(const bf16x8*)&Vt[(n2 * 16 + ln) * 232 + kc * 32 + quad * 8];
            o_acc[n2] = __builtin_amdgcn_mfma_f32_16x16x32_bf16(pf, vf, o_acc[n2], 0, 0, 0);
        }
    }

    // epilogue: x2 = xh + gamma1 * attn_out
    for (int n2 = 0; n2 < 2; n2++) {
        int c = head * 32 + n2 * 16 + ln;
        float g1 = gamma1[c];
        for (int r = 0; r < 4; r++) {
            int q = wave * 16 + quad * 4 + r;
            int hh = bh * 8 + (q >> 3), ww = bw * 8 + (q & 7);
            size_t p = (size_t)(b * 56 + hh) * 56 + ww;
            float a = o_acc[n2][r] * rinv[r];
            x2[p * 256 + c] = f2bf(bf2f(xh[p * 256 + c]) + g1 * a);
        }
    }
}

extern "C" void kernel_launch(void* const* d_in, const int* in_sizes, int n_in,
                              void* d_out, int out_size, void* d_ws, size_t ws_size,
                              hipStream_t stream) {
    const float* x      = (const float*)d_in[0];
    const float* ln1_g  = (const float*)d_in[1];
    const float* ln1_b  = (const float*)d_in[2];
    const float* wq     = (const float*)d_in[3];
    const float* bq     = (const float*)d_in[4];
    const float* wkv    = (const float*)d_in[5];
    const float* bkv    = (const float*)d_in[6];
    const float* bias   = (const float*)d_in[7];
    const float* gamma1 = (const float*)d_in[8];
    const float* ln2_g  = (const float*)d_in[9];
    const float* ln2_b  = (const float*)d_in[10];
    const float* w1     = (const float*)d_in[11];
    const float* b1     = (const float*)d_in[12];
    const float* w2     = (const float*)d_in[13];
    const float* b2     = (const float*)d_in[14];
    const float* gamma2 = (const float*)d_in[15];

    char* ws = (char*)d_ws;
    u16* qkv  = (u16*)ws;                      // 50176*768*2 = 77,070,336 B
    u16* xh   = (u16*)(ws + 77070336);         // 50176*256*2 = 25,690,112 B
    u16* xn   = (u16*)(ws + 102760448);        // 25,690,112 B
    u16* x2   = (u16*)(ws + 128450560);        // 25,690,112 B
    u16* hmid = (u16*)ws;                      // 50176*1024*2 aliases qkv+xh (both dead by then)

    // 1) NCHW f32 -> NHWC bf16 copy of raw x (residual source)
    k_transpose<<<dim3(49, 4, 16), 256, 0, stream>>>(x, xh);
    // 2) LN1
    k_ln<<<dim3(12544), 256, 0, stream>>>(xh, xn, ln1_g, ln1_b);
    // 3) QKV projection (fused q|kv GEMM, N=768)
    k_gemm<0><<<dim3(392, 6), 256, 0, stream>>>(xn, wq, wkv, bq, bkv, qkv, nullptr, nullptr, nullptr);
    // 4) halo attention + x2 = xh + gamma1*a
    k_attn<<<dim3(49, 8, 16), 256, 0, stream>>>(qkv, bias, xh, gamma1, x2);
    // 5) LN2
    k_ln<<<dim3(12544), 256, 0, stream>>>(x2, xn, ln2_g, ln2_b);
    // 6) MLP up + GELU (N=1024)
    k_gemm<1><<<dim3(392, 8), 256, 0, stream>>>(xn, w1, w1, b1, b1, hmid, nullptr, nullptr, nullptr);
    // 7) MLP down + gamma2 residual, store NCHW f32 to d_out
    k_gemm<2><<<dim3(392, 2), 256, 0, stream>>>(hmid, w2, w2, b2, b2, nullptr, x2, gamma2, (float*)d_out);
}

// Round 4
// 512.307 us; speedup vs baseline: 1.0236x; 1.0236x over previous
//
#include <hip/hip_runtime.h>
#include <hip/hip_bf16.h>
#include <math.h>

typedef unsigned short u16;
typedef float f32x4 __attribute__((ext_vector_type(4)));
typedef __bf16 bf16x8 __attribute__((ext_vector_type(8)));

__device__ __forceinline__ float bf2f(u16 u) {
    union { float f; unsigned int i; } v; v.i = ((unsigned int)u) << 16; return v.f;
}
__device__ __forceinline__ u16 f2bf(float f) {
    union { float f; unsigned int i; } v; v.f = f;
    unsigned int x = v.i;
    return (u16)((x + 0x7FFFu + ((x >> 16) & 1u)) >> 16);
}

// ---------------- K1: NCHW f32 -> NHWC bf16 transpose ----------------
// grid (49, 4, 16), block 256
__global__ __launch_bounds__(256) void k_transpose(const float* __restrict__ x, u16* __restrict__ xh) {
    __shared__ __align__(16) u16 tile[64][72];
    const int t = threadIdx.x;
    const int hw0 = blockIdx.x * 64;
    const int c0  = blockIdx.y * 64;
    const int b   = blockIdx.z;
    const int cl = t >> 2, wl = (t & 3) * 16;
    {
        int c = c0 + cl;
        const float* src = x + (size_t)(b * 256 + c) * 3136 + hw0 + wl;
        for (int q = 0; q < 4; q++) {
            float4 v = *(const float4*)(src + q * 4);
            u16* dst = &tile[cl][wl + q * 4];
            dst[0] = f2bf(v.x); dst[1] = f2bf(v.y); dst[2] = f2bf(v.z); dst[3] = f2bf(v.w);
        }
    }
    __syncthreads();
    const int hl = t >> 3, cl2 = (t & 7) * 8;
    for (int i = 0; i < 2; i++) {
        int hw = hl + i * 32;
        alignas(16) u16 tmp[8];
        for (int j = 0; j < 8; j++) tmp[j] = tile[cl2 + j][hw];
        u16* dst = xh + (size_t)(b * 3136 + hw0 + hw) * 256 + c0 + cl2;
        *(int4*)dst = *(int4*)tmp;
    }
}

// ---------------- K_stats: per-position LN stats (mean, rstd) over C=256 ----------------
// grid (12544), block 256 (4 waves, 1 position/wave)
__global__ __launch_bounds__(256) void k_stats(const u16* __restrict__ in,
                                               float* __restrict__ mu, float* __restrict__ rs) {
    const int wave = threadIdx.x >> 6, lane = threadIdx.x & 63;
    const int p = blockIdx.x * 4 + wave;
    ushort4 v = *(const ushort4*)(in + (size_t)p * 256 + lane * 4);
    float f0 = bf2f(v.x), f1 = bf2f(v.y), f2 = bf2f(v.z), f3 = bf2f(v.w);
    float s = f0 + f1 + f2 + f3;
    float sq = f0 * f0 + f1 * f1 + f2 * f2 + f3 * f3;
    for (int o = 32; o >= 1; o >>= 1) { s += __shfl_xor(s, o, 64); sq += __shfl_xor(sq, o, 64); }
    float m = s * (1.f / 256.f);
    float var = sq * (1.f / 256.f) - m * m;
    if (lane == 0) { mu[p] = m; rs[p] = rsqrtf(var + 1e-5f); }
}

// ---------------- GEMM: C[M,N] = LN(A)[M,K] @ B[N,K]^T (+epilogues) ----------------
// A: bf16, LN applied on the fly (MODE 0/1). B: f32 weights -> bf16 in staging.
// MODE 0: qkv = ln1(xh) @ [wq;wkv]^T + [bq;bkv]   (K=256, N=768)
// MODE 1: hmid = gelu(ln2(x2) @ w1^T + b1)        (K=256, N=1024)
// MODE 2: out_nchw(f32) = x2 + gamma2*(hmid @ w2^T + b2)  (K=1024, N=256)
// grid (NB, 392): bn = blockIdx.x (fast) so concurrent blocks share the A-tile.
template <int MODE>
__global__ __launch_bounds__(256) void k_gemm(
    const u16* __restrict__ Asrc,
    const float* __restrict__ mu, const float* __restrict__ rs,
    const float* __restrict__ lng, const float* __restrict__ lnb,
    const float* __restrict__ B0, const float* __restrict__ B1,
    const float* __restrict__ bias0, const float* __restrict__ bias1,
    u16* __restrict__ out,
    const u16* __restrict__ x2res, const float* __restrict__ g2v, float* __restrict__ outT) {
    constexpr int K = (MODE == 2) ? 1024 : 256;
    constexpr int NSPLIT = (MODE == 0) ? 256 : (1 << 30);
    constexpr int LDOUT = (MODE == 0) ? 768 : 1024;
    constexpr int SMEM_U16 = (MODE == 2) ? 8192 : 17408;  // MODE 0/1: C-tile 128x136 overlays As/Bs

    __shared__ __align__(16) u16 smem[SMEM_U16];
    u16* As = smem;          // 128*32
    u16* Bs = smem + 4096;   // 128*32

    const int t = threadIdx.x;
    const int bn = blockIdx.x, bm = blockIdx.y;
    const int wave = t >> 6, lane = t & 63;
    const int wm = (wave >> 1) * 64, wn = (wave & 1) * 64;
    const int ln = lane & 15, quad = lane >> 4;

    f32x4 vzero = {0.f, 0.f, 0.f, 0.f};
    f32x4 acc[4][4];
    for (int i = 0; i < 4; i++) for (int j = 0; j < 4; j++) acc[i][j] = vzero;

    const int srow = t >> 2;
    const int scol = (t & 3) * 8;

    float mur[2] = {0.f, 0.f}, rsr[2] = {0.f, 0.f};
    if (MODE != 2) {
        mur[0] = mu[bm * 128 + srow];      rsr[0] = rs[bm * 128 + srow];
        mur[1] = mu[bm * 128 + srow + 64]; rsr[1] = rs[bm * 128 + srow + 64];
    }

    for (int k0 = 0; k0 < K; k0 += 32) {
        if (MODE == 2) {
            for (int i = 0; i < 2; i++) {
                int r = srow + i * 64;
                *(int4*)&As[r * 32 + scol] = *(const int4*)(Asrc + (size_t)(bm * 128 + r) * K + k0 + scol);
            }
        } else {
            f32x4 g0 = *(const f32x4*)(lng + k0 + scol);
            f32x4 g1 = *(const f32x4*)(lng + k0 + scol + 4);
            f32x4 c0 = *(const f32x4*)(lnb + k0 + scol);
            f32x4 c1 = *(const f32x4*)(lnb + k0 + scol + 4);
            for (int i = 0; i < 2; i++) {
                int r = srow + i * 64;
                const u16* src = Asrc + (size_t)(bm * 128 + r) * 256 + k0 + scol;
                ushort4 x0 = *(const ushort4*)src;
                ushort4 x1 = *(const ushort4*)(src + 4);
                float m = mur[i], sc = rsr[i];
                alignas(16) u16 tmp[8];
                tmp[0] = f2bf((bf2f(x0.x) - m) * sc * g0[0] + c0[0]);
                tmp[1] = f2bf((bf2f(x0.y) - m) * sc * g0[1] + c0[1]);
                tmp[2] = f2bf((bf2f(x0.z) - m) * sc * g0[2] + c0[2]);
                tmp[3] = f2bf((bf2f(x0.w) - m) * sc * g0[3] + c0[3]);
                tmp[4] = f2bf((bf2f(x1.x) - m) * sc * g1[0] + c1[0]);
                tmp[5] = f2bf((bf2f(x1.y) - m) * sc * g1[1] + c1[1]);
                tmp[6] = f2bf((bf2f(x1.z) - m) * sc * g1[2] + c1[2]);
                tmp[7] = f2bf((bf2f(x1.w) - m) * sc * g1[3] + c1[3]);
                *(int4*)&As[r * 32 + scol] = *(int4*)tmp;
            }
        }
        for (int i = 0; i < 2; i++) {
            int r = srow + i * 64;
            int gn = bn * 128 + r;
            const float* bp = (gn < NSPLIT) ? (B0 + (size_t)gn * K) : (B1 + (size_t)(gn - NSPLIT) * K);
            float4 v0 = *(const float4*)(bp + k0 + scol);
            float4 v1 = *(const float4*)(bp + k0 + scol + 4);
            alignas(16) u16 tmp[8];
            tmp[0] = f2bf(v0.x); tmp[1] = f2bf(v0.y); tmp[2] = f2bf(v0.z); tmp[3] = f2bf(v0.w);
            tmp[4] = f2bf(v1.x); tmp[5] = f2bf(v1.y); tmp[6] = f2bf(v1.z); tmp[7] = f2bf(v1.w);
            *(int4*)&Bs[r * 32 + scol] = *(int4*)tmp;
        }
        __syncthreads();
        bf16x8 af[4], bfr[4];
        for (int mt = 0; mt < 4; mt++) af[mt] = *(const bf16x8*)&As[(wm + mt * 16 + ln) * 32 + quad * 8];
        for (int nt = 0; nt < 4; nt++) bfr[nt] = *(const bf16x8*)&Bs[(wn + nt * 16 + ln) * 32 + quad * 8];
        for (int mt = 0; mt < 4; mt++)
            for (int nt = 0; nt < 4; nt++) {
                if (MODE == 2)
                    acc[mt][nt] = __builtin_amdgcn_mfma_f32_16x16x32_bf16(af[mt], bfr[nt], acc[mt][nt], 0, 0, 0);
                else  // swapped: lane owns row gm=..+ln, cols gn=..+quad*4+r  -> coalesced epilogue
                    acc[mt][nt] = __builtin_amdgcn_mfma_f32_16x16x32_bf16(bfr[nt], af[mt], acc[mt][nt], 0, 0, 0);
            }
        __syncthreads();
    }

    if (MODE == 2) {
        // lane owns col gn (=..+ln) and 4 consecutive positions gm0..gm0+3 -> direct float4 store
        for (int nt = 0; nt < 4; nt++) {
            int gn = bn * 128 + wn + nt * 16 + ln;
            float bsv = bias0[gn];
            float g2 = g2v[gn];
            for (int mt = 0; mt < 4; mt++) {
                int gm0 = bm * 128 + wm + mt * 16 + quad * 4;
                int b = gm0 / 3136, hw0 = gm0 - b * 3136;
                f32x4 res;
                for (int r = 0; r < 4; r++) {
                    float v = acc[mt][nt][r] + bsv;
                    res[r] = bf2f(x2res[(size_t)(gm0 + r) * 256 + gn]) + g2 * v;
                }
                *(f32x4*)(outT + (size_t)(b * 256 + gn) * 3136 + hw0) = res;
            }
        }
    } else {
        // transposed D: lane owns row gm = wm+mt*16+ln, cols gn0..gn0+3
        u16* Cs = smem;  // [128][136]
        for (int nt = 0; nt < 4; nt++) {
            int gn0 = bn * 128 + wn + nt * 16 + quad * 4;
            const float* bp = (MODE == 0) ? ((gn0 < NSPLIT) ? (bias0 + gn0) : (bias1 + gn0 - NSPLIT))
                                          : (bias0 + gn0);
            f32x4 bv = *(const f32x4*)bp;
            for (int mt = 0; mt < 4; mt++) {
                ushort4 pk;
                float v0 = acc[mt][nt][0] + bv[0];
                float v1 = acc[mt][nt][1] + bv[1];
                float v2 = acc[mt][nt][2] + bv[2];
                float v3 = acc[mt][nt][3] + bv[3];
                if (MODE == 1) {
                    v0 = 0.5f * v0 * (1.f + erff(v0 * 0.70710678118654752f));
                    v1 = 0.5f * v1 * (1.f + erff(v1 * 0.70710678118654752f));
                    v2 = 0.5f * v2 * (1.f + erff(v2 * 0.70710678118654752f));
                    v3 = 0.5f * v3 * (1.f + erff(v3 * 0.70710678118654752f));
                }
                pk.x = f2bf(v0); pk.y = f2bf(v1); pk.z = f2bf(v2); pk.w = f2bf(v3);
                *(ushort4*)&Cs[(wm + mt * 16 + ln) * 136 + wn + nt * 16 + quad * 4] = pk;
            }
        }
        __syncthreads();
        const int row = t >> 4, col = (t & 15) * 8;
        for (int pass = 0; pass < 8; pass++) {
            int rr = pass * 16 + row;
            int4 v = *(int4*)&Cs[rr * 136 + col];
            *(int4*)(out + (size_t)(bm * 128 + rr) * LDOUT + bn * 128 + col) = v;
        }
    }
}

// ---------------- K4: halo attention + LayerScale residual ----------------
// grid (49, 8, 16), block 256 (4 waves, wave = 16-query m-tile)
__global__ __launch_bounds__(256) void k_attn(
    const u16* __restrict__ qkv, const float* __restrict__ bias,
    const u16* __restrict__ xh, const float* __restrict__ gamma1,
    u16* __restrict__ x2) {
    __shared__ __align__(16) u16 Kl[208 * 40];      // K[k_pos][d], padded stride
    __shared__ __align__(16) u16 Vt[32 * 232];      // V^T[d][k_pos]
    __shared__ __align__(16) u16 Pl[4][16 * 232];   // per-wave P[q][k_pos]

    const int t = threadIdx.x;
    const int blk = blockIdx.x, head = blockIdx.y, b = blockIdx.z;
    const int bh = blk / 7, bw = blk - bh * 7;
    const int wave = t >> 6, lane = t & 63;
    const int ln = lane & 15, quad = lane >> 4;

    {
        int4 z = {0, 0, 0, 0};
        for (int i = t; i < (32 * 232) / 8; i += 256) ((int4*)Vt)[i] = z;
        for (int i = t; i < (4 * 16 * 232) / 8; i += 256) ((int4*)&Pl[0][0])[i] = z;
    }
    __syncthreads();

    for (int cid = t; cid < 208 * 8; cid += 256) {
        int pos = cid >> 3, part = cid & 7;
        int i = pos / 14, j = pos - i * 14;
        int gh = bh * 8 - 3 + i, gw = bw * 8 - 3 + j;
        bool valid = (pos < 196) && ((unsigned)gh < 56u) && ((unsigned)gw < 56u);
        int d0 = (part & 3) * 8;
        int4 v = {0, 0, 0, 0};
        if (valid) {
            size_t p = (size_t)(b * 56 + gh) * 56 + gw;
            v = *(const int4*)(qkv + p * 768 + 256 + head * 64 + ((part & 4) ? 32 : 0) + d0);
        }
        if (!(part & 4)) {
            *(int4*)&Kl[pos * 40 + d0] = v;
        } else {
            alignas(16) u16 tmp[8];
            *(int4*)tmp = v;
            for (int jj = 0; jj < 8; jj++) Vt[(d0 + jj) * 232 + pos] = tmp[jj];
        }
    }
    __syncthreads();

    const int qrow = wave * 16 + ln;
    const int qh = bh * 8 + (qrow >> 3), qw = bw * 8 + (qrow & 7);
    const size_t qp = (size_t)(b * 56 + qh) * 56 + qw;
    bf16x8 qf = *(const bf16x8*)(qkv + qp * 768 + head * 32 + quad * 8);

    f32x4 vzero = {0.f, 0.f, 0.f, 0.f};
    float sv[13][4];
    float mx[4] = {-1e30f, -1e30f, -1e30f, -1e30f};
    const float scale = 0.17677669529663687f;  // 1/sqrt(32)
    for (int nt = 0; nt < 13; nt++) {
        bf16x8 kf = *(const bf16x8*)&Kl[(nt * 16 + ln) * 40 + quad * 8];
        f32x4 s = __builtin_amdgcn_mfma_f32_16x16x32_bf16(qf, kf, vzero, 0, 0, 0);
        int kk = nt * 16 + ln;
        bool kvalid = kk < 196;
        for (int r = 0; r < 4; r++) {
            int qq = wave * 16 + quad * 4 + r;
            float val = kvalid ? (s[r] * scale + bias[(size_t)(head * 64 + qq) * 196 + kk]) : -1e30f;
            sv[nt][r] = val;
            mx[r] = fmaxf(mx[r], val);
        }
    }
    for (int o = 1; o < 16; o <<= 1)
        for (int r = 0; r < 4; r++) mx[r] = fmaxf(mx[r], __shfl_xor(mx[r], o, 16));
    float sum[4] = {0.f, 0.f, 0.f, 0.f};
    for (int nt = 0; nt < 13; nt++)
        for (int r = 0; r < 4; r++) {
            float e = __expf(sv[nt][r] - mx[r]);
            sv[nt][r] = e;
            sum[r] += e;
        }
    for (int o = 1; o < 16; o <<= 1)
        for (int r = 0; r < 4; r++) sum[r] += __shfl_xor(sum[r], o, 16);
    float rinv[4];
    for (int r = 0; r < 4; r++) rinv[r] = 1.f / sum[r];

    u16* plw = &Pl[wave][0];
    for (int nt = 0; nt < 13; nt++)
        for (int r = 0; r < 4; r++)
            plw[(quad * 4 + r) * 232 + nt * 16 + ln] = f2bf(sv[nt][r]);
    __syncthreads();

    f32x4 o_acc[2];
    o_acc[0] = vzero; o_acc[1] = vzero;
    for (int kc = 0; kc < 7; kc++) {
        bf16x8 pf = *(const bf16x8*)&plw[ln * 232 + kc * 32 + quad * 8];
        for (int n2 = 0; n2 < 2; n2++) {
            bf16x8 vf = *(const bf16x8*)&Vt[(n2 * 16 + ln) * 232 + kc * 32 + quad * 8];
            o_acc[n2] = __builtin_amdgcn_mfma_f32_16x16x32_bf16(pf, vf, o_acc[n2], 0, 0, 0);
        }
    }

    for (int n2 = 0; n2 < 2; n2++) {
        int c = head * 32 + n2 * 16 + ln;
        float g1 = gamma1[c];
        for (int r = 0; r < 4; r++) {
            int q = wave * 16 + quad * 4 + r;
            int hh = bh * 8 + (q >> 3), ww = bw * 8 + (q & 7);
            size_t p = (size_t)(b * 56 + hh) * 56 + ww;
            float a = o_acc[n2][r] * rinv[r];
            x2[p * 256 + c] = f2bf(bf2f(xh[p * 256 + c]) + g1 * a);
        }
    }
}

extern "C" void kernel_launch(void* const* d_in, const int* in_sizes, int n_in,
                              void* d_out, int out_size, void* d_ws, size_t ws_size,
                              hipStream_t stream) {
    const float* x      = (const float*)d_in[0];
    const float* ln1_g  = (const float*)d_in[1];
    const float* ln1_b  = (const float*)d_in[2];
    const float* wq     = (const float*)d_in[3];
    const float* bq     = (const float*)d_in[4];
    const float* wkv    = (const float*)d_in[5];
    const float* bkv    = (const float*)d_in[6];
    const float* bias   = (const float*)d_in[7];
    const float* gamma1 = (const float*)d_in[8];
    const float* ln2_g  = (const float*)d_in[9];
    const float* ln2_b  = (const float*)d_in[10];
    const float* w1     = (const float*)d_in[11];
    const float* b1     = (const float*)d_in[12];
    const float* w2     = (const float*)d_in[13];
    const float* b2     = (const float*)d_in[14];
    const float* gamma2 = (const float*)d_in[15];

    char* ws = (char*)d_ws;
    u16* qkv   = (u16*)ws;                       // 77,070,336 B
    u16* xh    = (u16*)(ws + 77070336);          // 25,690,112 B
    u16* x2    = (u16*)(ws + 102760448);         // 25,690,112 B
    float* mu1 = (float*)(ws + 128450560);       // 200,704 B
    float* rs1 = (float*)(ws + 128651264);
    float* mu2 = (float*)(ws + 128851968);
    float* rs2 = (float*)(ws + 129052672);
    u16* hmid  = (u16*)ws;                       // 102,760,448 B, aliases qkv+xh (dead by then)

    k_transpose<<<dim3(49, 4, 16), 256, 0, stream>>>(x, xh);
    k_stats<<<dim3(12544), 256, 0, stream>>>(xh, mu1, rs1);
    k_gemm<0><<<dim3(6, 392), 256, 0, stream>>>(xh, mu1, rs1, ln1_g, ln1_b, wq, wkv, bq, bkv,
                                                qkv, nullptr, nullptr, nullptr);
    k_attn<<<dim3(49, 8, 16), 256, 0, stream>>>(qkv, bias, xh, gamma1, x2);
    k_stats<<<dim3(12544), 256, 0, stream>>>(x2, mu2, rs2);
    k_gemm<1><<<dim3(8, 392), 256, 0, stream>>>(x2, mu2, rs2, ln2_g, ln2_b, w1, w1, b1, b1,
                                                hmid, nullptr, nullptr, nullptr);
    k_gemm<2><<<dim3(2, 392), 256, 0, stream>>>(hmid, nullptr, nullptr, nullptr, nullptr, w2, w2, b2, b2,
                                                nullptr, x2, gamma2, (float*)d_out);
}

// Round 5
// 458.063 us; speedup vs baseline: 1.1448x; 1.1184x over previous
//
#include <hip/hip_runtime.h>
#include <hip/hip_bf16.h>
#include <math.h>

typedef unsigned short u16;
typedef float f32x4 __attribute__((ext_vector_type(4)));
typedef __bf16 bf16x8 __attribute__((ext_vector_type(8)));

__device__ __forceinline__ float bf2f(u16 u) {
    union { float f; unsigned int i; } v; v.i = ((unsigned int)u) << 16; return v.f;
}
__device__ __forceinline__ u16 f2bf(float f) {
    union { float f; unsigned int i; } v; v.f = f;
    unsigned int x = v.i;
    return (u16)((x + 0x7FFFu + ((x >> 16) & 1u)) >> 16);
}

// ---------------- K0: one-time f32 -> bf16 weight conversion ----------------
// wqkvb[768][256] = [wq;wkv]; w1b[1024][256]; w2b[256][1024]. grid 704*256 threads, 4 elems each.
__global__ __launch_bounds__(256) void k_prep(const float* __restrict__ wq, const float* __restrict__ wkv,
                                              const float* __restrict__ w1, const float* __restrict__ w2,
                                              u16* __restrict__ wqkvb, u16* __restrict__ w1b, u16* __restrict__ w2b) {
    int e = (blockIdx.x * 256 + threadIdx.x) * 4;
    const float* src;
    u16* dst;
    if (e < 196608) {
        src = (e < 65536) ? (wq + e) : (wkv + (e - 65536));
        dst = wqkvb + e;
    } else if (e < 458752) {
        src = w1 + (e - 196608);
        dst = w1b + (e - 196608);
    } else {
        src = w2 + (e - 458752);
        dst = w2b + (e - 458752);
    }
    float4 v = *(const float4*)src;
    ushort4 o;
    o.x = f2bf(v.x); o.y = f2bf(v.y); o.z = f2bf(v.z); o.w = f2bf(v.w);
    *(ushort4*)dst = o;
}

// ---------------- K1: NCHW f32 -> NHWC bf16 transpose ----------------
__global__ __launch_bounds__(256) void k_transpose(const float* __restrict__ x, u16* __restrict__ xh) {
    __shared__ __align__(16) u16 tile[64][72];
    const int t = threadIdx.x;
    const int hw0 = blockIdx.x * 64;
    const int c0  = blockIdx.y * 64;
    const int b   = blockIdx.z;
    const int cl = t >> 2, wl = (t & 3) * 16;
    {
        int c = c0 + cl;
        const float* src = x + (size_t)(b * 256 + c) * 3136 + hw0 + wl;
        for (int q = 0; q < 4; q++) {
            float4 v = *(const float4*)(src + q * 4);
            u16* dst = &tile[cl][wl + q * 4];
            dst[0] = f2bf(v.x); dst[1] = f2bf(v.y); dst[2] = f2bf(v.z); dst[3] = f2bf(v.w);
        }
    }
    __syncthreads();
    const int hl = t >> 3, cl2 = (t & 7) * 8;
    for (int i = 0; i < 2; i++) {
        int hw = hl + i * 32;
        alignas(16) u16 tmp[8];
        for (int j = 0; j < 8; j++) tmp[j] = tile[cl2 + j][hw];
        u16* dst = xh + (size_t)(b * 3136 + hw0 + hw) * 256 + c0 + cl2;
        *(int4*)dst = *(int4*)tmp;
    }
}

// ---------------- K_stats: per-position LN stats over C=256 ----------------
__global__ __launch_bounds__(256) void k_stats(const u16* __restrict__ in,
                                               float* __restrict__ mu, float* __restrict__ rs) {
    const int wave = threadIdx.x >> 6, lane = threadIdx.x & 63;
    const int p = blockIdx.x * 4 + wave;
    ushort4 v = *(const ushort4*)(in + (size_t)p * 256 + lane * 4);
    float f0 = bf2f(v.x), f1 = bf2f(v.y), f2 = bf2f(v.z), f3 = bf2f(v.w);
    float s = f0 + f1 + f2 + f3;
    float sq = f0 * f0 + f1 * f1 + f2 * f2 + f3 * f3;
    for (int o = 32; o >= 1; o >>= 1) { s += __shfl_xor(s, o, 64); sq += __shfl_xor(sq, o, 64); }
    float m = s * (1.f / 256.f);
    float var = sq * (1.f / 256.f) - m * m;
    if (lane == 0) { mu[p] = m; rs[p] = rsqrtf(var + 1e-5f); }
}

// ---------------- K_qkv: qkv = ln1(xh) @ wqkvb^T + [bq;bkv] ----------------
// grid 2352 1D, XCD-swizzled: each XCD owns a contiguous bm range (A-tile L2-local).
__global__ __launch_bounds__(256) void k_qkv(
    const u16* __restrict__ Asrc, const float* __restrict__ mu, const float* __restrict__ rs,
    const float* __restrict__ lng, const float* __restrict__ lnb,
    const u16* __restrict__ Bw, const float* __restrict__ bq, const float* __restrict__ bkv,
    u16* __restrict__ out) {
    __shared__ __align__(16) u16 smem[17408];
    u16* As = smem;          // 128*32
    u16* Bs = smem + 4096;   // 128*32

    const int g = blockIdx.x;
    const int xcd = g & 7, idx = g >> 3;
    const int bm = xcd * 49 + idx / 6, bn = idx % 6;

    const int t = threadIdx.x;
    const int wave = t >> 6, lane = t & 63;
    const int wm = (wave >> 1) * 64, wn = (wave & 1) * 64;
    const int ln = lane & 15, quad = lane >> 4;

    f32x4 vzero = {0.f, 0.f, 0.f, 0.f};
    f32x4 acc[4][4];
    for (int i = 0; i < 4; i++) for (int j = 0; j < 4; j++) acc[i][j] = vzero;

    const int srow = t >> 2;
    const int scol = (t & 3) * 8;
    float mur[2], rsr[2];
    mur[0] = mu[bm * 128 + srow];      rsr[0] = rs[bm * 128 + srow];
    mur[1] = mu[bm * 128 + srow + 64]; rsr[1] = rs[bm * 128 + srow + 64];

    for (int k0 = 0; k0 < 256; k0 += 32) {
        f32x4 g0 = *(const f32x4*)(lng + k0 + scol);
        f32x4 g1 = *(const f32x4*)(lng + k0 + scol + 4);
        f32x4 c0 = *(const f32x4*)(lnb + k0 + scol);
        f32x4 c1 = *(const f32x4*)(lnb + k0 + scol + 4);
        for (int i = 0; i < 2; i++) {
            int r = srow + i * 64;
            const u16* src = Asrc + (size_t)(bm * 128 + r) * 256 + k0 + scol;
            ushort4 x0 = *(const ushort4*)src;
            ushort4 x1 = *(const ushort4*)(src + 4);
            float m = mur[i], sc = rsr[i];
            alignas(16) u16 tmp[8];
            tmp[0] = f2bf((bf2f(x0.x) - m) * sc * g0[0] + c0[0]);
            tmp[1] = f2bf((bf2f(x0.y) - m) * sc * g0[1] + c0[1]);
            tmp[2] = f2bf((bf2f(x0.z) - m) * sc * g0[2] + c0[2]);
            tmp[3] = f2bf((bf2f(x0.w) - m) * sc * g0[3] + c0[3]);
            tmp[4] = f2bf((bf2f(x1.x) - m) * sc * g1[0] + c1[0]);
            tmp[5] = f2bf((bf2f(x1.y) - m) * sc * g1[1] + c1[1]);
            tmp[6] = f2bf((bf2f(x1.z) - m) * sc * g1[2] + c1[2]);
            tmp[7] = f2bf((bf2f(x1.w) - m) * sc * g1[3] + c1[3]);
            *(int4*)&As[r * 32 + scol] = *(int4*)tmp;
        }
        for (int i = 0; i < 2; i++) {
            int r = srow + i * 64;
            *(int4*)&Bs[r * 32 + scol] = *(const int4*)(Bw + (size_t)(bn * 128 + r) * 256 + k0 + scol);
        }
        __syncthreads();
        bf16x8 af[4], bfr[4];
        for (int mt = 0; mt < 4; mt++) af[mt] = *(const bf16x8*)&As[(wm + mt * 16 + ln) * 32 + quad * 8];
        for (int nt = 0; nt < 4; nt++) bfr[nt] = *(const bf16x8*)&Bs[(wn + nt * 16 + ln) * 32 + quad * 8];
        for (int mt = 0; mt < 4; mt++)
            for (int nt = 0; nt < 4; nt++)   // swapped: lane owns row (m), 4 consecutive cols
                acc[mt][nt] = __builtin_amdgcn_mfma_f32_16x16x32_bf16(bfr[nt], af[mt], acc[mt][nt], 0, 0, 0);
        __syncthreads();
    }

    u16* Cs = smem;  // [128][136]
    for (int nt = 0; nt < 4; nt++) {
        int gn0 = bn * 128 + wn + nt * 16 + quad * 4;
        f32x4 bv = (gn0 < 256) ? *(const f32x4*)(bq + gn0) : *(const f32x4*)(bkv + gn0 - 256);
        for (int mt = 0; mt < 4; mt++) {
            ushort4 pk;
            pk.x = f2bf(acc[mt][nt][0] + bv[0]);
            pk.y = f2bf(acc[mt][nt][1] + bv[1]);
            pk.z = f2bf(acc[mt][nt][2] + bv[2]);
            pk.w = f2bf(acc[mt][nt][3] + bv[3]);
            *(ushort4*)&Cs[(wm + mt * 16 + ln) * 136 + wn + nt * 16 + quad * 4] = pk;
        }
    }
    __syncthreads();
    const int row = t >> 4, col = (t & 15) * 8;
    for (int pass = 0; pass < 8; pass++) {
        int rr = pass * 16 + row;
        int4 v = *(int4*)&Cs[rr * 136 + col];
        *(int4*)(out + (size_t)(bm * 128 + rr) * 768 + bn * 128 + col) = v;
    }
}

// ---------------- K_mlp: fused out = x2 + g2*(gelu(ln2(x2)@w1^T+b1)@w2^T+b2), NCHW f32 ----------------
// grid 784 1D XCD-swizzled; block = 64 positions. hmid never hits HBM.
__global__ __launch_bounds__(256) void k_mlp(
    const u16* __restrict__ x2, const float* __restrict__ mu, const float* __restrict__ rs,
    const float* __restrict__ lng, const float* __restrict__ lnb,
    const u16* __restrict__ w1b, const float* __restrict__ b1,
    const u16* __restrict__ w2b, const float* __restrict__ b2,
    const float* __restrict__ g2v, float* __restrict__ outT) {
    __shared__ __align__(16) u16 smem[16896 + 4608];  // As 64x264, Hs 64x72
    u16* As = smem;
    u16* Hs = smem + 16896;

    const int g = blockIdx.x;
    const int bm = (g & 7) * 98 + (g >> 3);

    const int t = threadIdx.x;
    const int wave = t >> 6, lane = t & 63;
    const int ln = lane & 15, quad = lane >> 4;
    const int wn16 = wave * 16, wn64 = wave * 64;

    f32x4 vzero = {0.f, 0.f, 0.f, 0.f};
    f32x4 acc[4][4];  // out tile: [mt][nt], lane: n = wn64+nt*16+ln, m = mt*16+quad*4+r
    for (int i = 0; i < 4; i++) for (int j = 0; j < 4; j++) acc[i][j] = vzero;

    // stage A = ln2(x2 tile) into LDS (64 rows x 256, stride 264)
    {
        const int srow = t >> 2, scb = (t & 3) * 8;
        float m = mu[bm * 64 + srow], sc = rs[bm * 64 + srow];
        for (int c = 0; c < 8; c++) {
            int col = scb + c * 32;
            f32x4 g0 = *(const f32x4*)(lng + col);
            f32x4 g1 = *(const f32x4*)(lng + col + 4);
            f32x4 c0 = *(const f32x4*)(lnb + col);
            f32x4 c1 = *(const f32x4*)(lnb + col + 4);
            const u16* src = x2 + (size_t)(bm * 64 + srow) * 256 + col;
            ushort4 x0 = *(const ushort4*)src;
            ushort4 x1 = *(const ushort4*)(src + 4);
            alignas(16) u16 tmp[8];
            tmp[0] = f2bf((bf2f(x0.x) - m) * sc * g0[0] + c0[0]);
            tmp[1] = f2bf((bf2f(x0.y) - m) * sc * g0[1] + c0[1]);
            tmp[2] = f2bf((bf2f(x0.z) - m) * sc * g0[2] + c0[2]);
            tmp[3] = f2bf((bf2f(x0.w) - m) * sc * g0[3] + c0[3]);
            tmp[4] = f2bf((bf2f(x1.x) - m) * sc * g1[0] + c1[0]);
            tmp[5] = f2bf((bf2f(x1.y) - m) * sc * g1[1] + c1[1]);
            tmp[6] = f2bf((bf2f(x1.z) - m) * sc * g1[2] + c1[2]);
            tmp[7] = f2bf((bf2f(x1.w) - m) * sc * g1[3] + c1[3]);
            *(int4*)&As[srow * 264 + col] = *(int4*)tmp;
        }
    }
    __syncthreads();

    for (int kc = 0; kc < 16; kc++) {
        // ---- up: H[64m x 64n] chunk; wave owns n-slice wn16. W1 frags direct from L2. ----
        f32x4 up[4];
        for (int i = 0; i < 4; i++) up[i] = vzero;
        bf16x8 w1f[8];
        const u16* w1row = w1b + (size_t)(kc * 64 + wn16 + ln) * 256 + quad * 8;
        for (int ks = 0; ks < 8; ks++) w1f[ks] = *(const bf16x8*)(w1row + ks * 32);
        for (int ks = 0; ks < 8; ks++) {
            for (int mt = 0; mt < 4; mt++) {
                bf16x8 af = *(const bf16x8*)&As[(mt * 16 + ln) * 264 + ks * 32 + quad * 8];
                up[mt] = __builtin_amdgcn_mfma_f32_16x16x32_bf16(af, w1f[ks], up[mt], 0, 0, 0);
            }
        }
        // gelu (fast sigmoid form; contribution scaled by gamma2=1e-6) + write H to LDS
        float bv = b1[kc * 64 + wn16 + ln];
        for (int mt = 0; mt < 4; mt++)
            for (int r = 0; r < 4; r++) {
                float v = up[mt][r] + bv;
                float s = 1.f / (1.f + __expf(-1.702f * v));
                Hs[(mt * 16 + quad * 4 + r) * 72 + wn16 + ln] = f2bf(v * s);
            }
        __syncthreads();
        // ---- down: acc += H @ W2c^T; wave owns n-slice wn64. W2 frags direct from L2. ----
        for (int ks2 = 0; ks2 < 2; ks2++) {
            bf16x8 hf[4];
            for (int mt = 0; mt < 4; mt++)
                hf[mt] = *(const bf16x8*)&Hs[(mt * 16 + ln) * 72 + ks2 * 32 + quad * 8];
            for (int nt = 0; nt < 4; nt++) {
                bf16x8 w2f = *(const bf16x8*)(w2b + (size_t)(wn64 + nt * 16 + ln) * 1024 + kc * 64 + ks2 * 32 + quad * 8);
                for (int mt = 0; mt < 4; mt++)
                    acc[mt][nt] = __builtin_amdgcn_mfma_f32_16x16x32_bf16(hf[mt], w2f, acc[mt][nt], 0, 0, 0);
            }
        }
        __syncthreads();  // protect Hs before next chunk overwrites
    }

    // epilogue: lane owns channel gn, 4 consecutive positions -> float4 NCHW store
    const int b = bm / 49;
    for (int nt = 0; nt < 4; nt++) {
        int gn = wn64 + nt * 16 + ln;
        float bs = b2[gn], g2 = g2v[gn];
        for (int mt = 0; mt < 4; mt++) {
            int gm0 = bm * 64 + mt * 16 + quad * 4;
            int hw0 = gm0 - b * 3136;
            f32x4 res;
            for (int r = 0; r < 4; r++)
                res[r] = bf2f(x2[(size_t)(gm0 + r) * 256 + gn]) + g2 * (acc[mt][nt][r] + bs);
            *(f32x4*)(outT + (size_t)(b * 256 + gn) * 3136 + hw0) = res;
        }
    }
}

// ---------------- K_attn: halo attention + LayerScale residual ----------------
__global__ __launch_bounds__(256) void k_attn(
    const u16* __restrict__ qkv, const float* __restrict__ bias,
    const u16* __restrict__ xh, const float* __restrict__ gamma1,
    u16* __restrict__ x2) {
    __shared__ __align__(16) u16 Kl[208 * 40];
    __shared__ __align__(16) u16 Vt[32 * 232];
    __shared__ __align__(16) u16 Pl[4][16 * 232];

    const int t = threadIdx.x;
    const int blk = blockIdx.x, head = blockIdx.y, b = blockIdx.z;
    const int bh = blk / 7, bw = blk - bh * 7;
    const int wave = t >> 6, lane = t & 63;
    const int ln = lane & 15, quad = lane >> 4;

    {
        int4 z = {0, 0, 0, 0};
        for (int i = t; i < (32 * 232) / 8; i += 256) ((int4*)Vt)[i] = z;
        for (int i = t; i < (4 * 16 * 232) / 8; i += 256) ((int4*)&Pl[0][0])[i] = z;
    }
    __syncthreads();

    for (int cid = t; cid < 208 * 8; cid += 256) {
        int pos = cid >> 3, part = cid & 7;
        int i = pos / 14, j = pos - i * 14;
        int gh = bh * 8 - 3 + i, gw = bw * 8 - 3 + j;
        bool valid = (pos < 196) && ((unsigned)gh < 56u) && ((unsigned)gw < 56u);
        int d0 = (part & 3) * 8;
        int4 v = {0, 0, 0, 0};
        if (valid) {
            size_t p = (size_t)(b * 56 + gh) * 56 + gw;
            v = *(const int4*)(qkv + p * 768 + 256 + head * 64 + ((part & 4) ? 32 : 0) + d0);
        }
        if (!(part & 4)) {
            *(int4*)&Kl[pos * 40 + d0] = v;
        } else {
            alignas(16) u16 tmp[8];
            *(int4*)tmp = v;
            for (int jj = 0; jj < 8; jj++) Vt[(d0 + jj) * 232 + pos] = tmp[jj];
        }
    }
    __syncthreads();

    const int qrow = wave * 16 + ln;
    const int qh = bh * 8 + (qrow >> 3), qw = bw * 8 + (qrow & 7);
    const size_t qp = (size_t)(b * 56 + qh) * 56 + qw;
    bf16x8 qf = *(const bf16x8*)(qkv + qp * 768 + head * 32 + quad * 8);

    f32x4 vzero = {0.f, 0.f, 0.f, 0.f};
    float sv[13][4];
    float mx[4] = {-1e30f, -1e30f, -1e30f, -1e30f};
    const float scale = 0.17677669529663687f;
    for (int nt = 0; nt < 13; nt++) {
        bf16x8 kf = *(const bf16x8*)&Kl[(nt * 16 + ln) * 40 + quad * 8];
        f32x4 s = __builtin_amdgcn_mfma_f32_16x16x32_bf16(qf, kf, vzero, 0, 0, 0);
        int kk = nt * 16 + ln;
        bool kvalid = kk < 196;
        for (int r = 0; r < 4; r++) {
            int qq = wave * 16 + quad * 4 + r;
            float val = kvalid ? (s[r] * scale + bias[(size_t)(head * 64 + qq) * 196 + kk]) : -1e30f;
            sv[nt][r] = val;
            mx[r] = fmaxf(mx[r], val);
        }
    }
    for (int o = 1; o < 16; o <<= 1)
        for (int r = 0; r < 4; r++) mx[r] = fmaxf(mx[r], __shfl_xor(mx[r], o, 16));
    float sum[4] = {0.f, 0.f, 0.f, 0.f};
    for (int nt = 0; nt < 13; nt++)
        for (int r = 0; r < 4; r++) {
            float e = __expf(sv[nt][r] - mx[r]);
            sv[nt][r] = e;
            sum[r] += e;
        }
    for (int o = 1; o < 16; o <<= 1)
        for (int r = 0; r < 4; r++) sum[r] += __shfl_xor(sum[r], o, 16);
    float rinv[4];
    for (int r = 0; r < 4; r++) rinv[r] = 1.f / sum[r];

    u16* plw = &Pl[wave][0];
    for (int nt = 0; nt < 13; nt++)
        for (int r = 0; r < 4; r++)
            plw[(quad * 4 + r) * 232 + nt * 16 + ln] = f2bf(sv[nt][r]);
    __syncthreads();

    f32x4 o_acc[2];
    o_acc[0] = vzero; o_acc[1] = vzero;
    for (int kc = 0; kc < 7; kc++) {
        bf16x8 pf = *(const bf16x8*)&plw[ln * 232 + kc * 32 + quad * 8];
        for (int n2 = 0; n2 < 2; n2++) {
            bf16x8 vf = *(const bf16x8*)&Vt[(n2 * 16 + ln) * 232 + kc * 32 + quad * 8];
            o_acc[n2] = __builtin_amdgcn_mfma_f32_16x16x32_bf16(pf, vf, o_acc[n2], 0, 0, 0);
        }
    }

    for (int n2 = 0; n2 < 2; n2++) {
        int c = head * 32 + n2 * 16 + ln;
        float g1 = gamma1[c];
        for (int r = 0; r < 4; r++) {
            int q = wave * 16 + quad * 4 + r;
            int hh = bh * 8 + (q >> 3), ww = bw * 8 + (q & 7);
            size_t p = (size_t)(b * 56 + hh) * 56 + ww;
            float a = o_acc[n2][r] * rinv[r];
            x2[p * 256 + c] = f2bf(bf2f(xh[p * 256 + c]) + g1 * a);
        }
    }
}

extern "C" void kernel_launch(void* const* d_in, const int* in_sizes, int n_in,
                              void* d_out, int out_size, void* d_ws, size_t ws_size,
                              hipStream_t stream) {
    const float* x      = (const float*)d_in[0];
    const float* ln1_g  = (const float*)d_in[1];
    const float* ln1_b  = (const float*)d_in[2];
    const float* wq     = (const float*)d_in[3];
    const float* bq     = (const float*)d_in[4];
    const float* wkv    = (const float*)d_in[5];
    const float* bkv    = (const float*)d_in[6];
    const float* bias   = (const float*)d_in[7];
    const float* gamma1 = (const float*)d_in[8];
    const float* ln2_g  = (const float*)d_in[9];
    const float* ln2_b  = (const float*)d_in[10];
    const float* w1     = (const float*)d_in[11];
    const float* b1     = (const float*)d_in[12];
    const float* w2     = (const float*)d_in[13];
    const float* b2     = (const float*)d_in[14];
    const float* gamma2 = (const float*)d_in[15];

    char* ws = (char*)d_ws;
    u16* qkv    = (u16*)ws;                      // 77,070,336 B
    u16* xh     = (u16*)(ws + 77070336);         // 25,690,112 B
    u16* x2     = (u16*)(ws + 102760448);        // 25,690,112 B
    float* mu1  = (float*)(ws + 128450560);
    float* rs1  = (float*)(ws + 128651264);
    float* mu2  = (float*)(ws + 128851968);
    float* rs2  = (float*)(ws + 129052672);
    u16* wqkvb  = (u16*)(ws + 129253376);        // 393,216 B
    u16* w1b    = (u16*)(ws + 129646592);        // 524,288 B
    u16* w2b    = (u16*)(ws + 130170880);        // 524,288 B

    k_prep<<<dim3(704), 256, 0, stream>>>(wq, wkv, w1, w2, wqkvb, w1b, w2b);
    k_transpose<<<dim3(49, 4, 16), 256, 0, stream>>>(x, xh);
    k_stats<<<dim3(12544), 256, 0, stream>>>(xh, mu1, rs1);
    k_qkv<<<dim3(2352), 256, 0, stream>>>(xh, mu1, rs1, ln1_g, ln1_b, wqkvb, bq, bkv, qkv);
    k_attn<<<dim3(49, 8, 16), 256, 0, stream>>>(qkv, bias, xh, gamma1, x2);
    k_stats<<<dim3(12544), 256, 0, stream>>>(x2, mu2, rs2);
    k_mlp<<<dim3(784), 256, 0, stream>>>(x2, mu2, rs2, ln2_g, ln2_b, w1b, b1, w2b, b2, gamma2, (float*)d_out);
}

// Round 7
// 435.664 us; speedup vs baseline: 1.2036x; 1.0514x over previous
//
#include <hip/hip_runtime.h>
#include <hip/hip_bf16.h>
#include <math.h>

typedef unsigned short u16;
typedef float f32x4 __attribute__((ext_vector_type(4)));
typedef __bf16 bf16x8 __attribute__((ext_vector_type(8)));

__device__ __forceinline__ float bf2f(u16 u) {
    union { float f; unsigned int i; } v; v.i = ((unsigned int)u) << 16; return v.f;
}
__device__ __forceinline__ u16 f2bf(float f) {
    union { float f; unsigned int i; } v; v.f = f;
    unsigned int x = v.i;
    return (u16)((x + 0x7FFFu + ((x >> 16) & 1u)) >> 16);
}

// ---------------- K0: one-time weight conversion + fragment reordering ----------------
// bid [0,192): wqkvb[768][256] row-major bf16.
// bid [192,320): w1p fragment order [kc16][wave4][ks8][lane64][8]  (up B-frag: n=kc*64+wave*16+ln, k=ks*32+quad*8+j)
// bid [320,448): w2p fragment order [kc16][wave4][ks2_2][nt4][lane64][8] (down B-frag: n=wave*64+nt*16+ln, k=kc*64+ks2*32+quad*8+j)
__global__ __launch_bounds__(256) void k_prep(const float* __restrict__ wq, const float* __restrict__ wkv,
                                              const float* __restrict__ w1, const float* __restrict__ w2,
                                              u16* __restrict__ wqkvb, u16* __restrict__ w1p, u16* __restrict__ w2p) {
    const int bid = blockIdx.x, t = threadIdx.x;
    if (bid < 192) {
        int e = (bid * 256 + t) * 4;
        const float* src = (e < 65536) ? (wq + e) : (wkv + (e - 65536));
        float4 v = *(const float4*)src;
        ushort4 o;
        o.x = f2bf(v.x); o.y = f2bf(v.y); o.z = f2bf(v.z); o.w = f2bf(v.w);
        *(ushort4*)(wqkvb + e) = o;
    } else if (bid < 320) {
        int tid = (bid - 192) * 256 + t;
        int kc = tid >> 11, rem = tid & 2047;
        int wave = rem >> 9, rem2 = rem & 511;
        int ks = rem2 >> 6, lane = rem2 & 63;
        int ln = lane & 15, quad = lane >> 4;
        const float* src = w1 + (size_t)(kc * 64 + wave * 16 + ln) * 256 + ks * 32 + quad * 8;
        float4 v0 = *(const float4*)src;
        float4 v1 = *(const float4*)(src + 4);
        alignas(16) u16 tmp[8];
        tmp[0] = f2bf(v0.x); tmp[1] = f2bf(v0.y); tmp[2] = f2bf(v0.z); tmp[3] = f2bf(v0.w);
        tmp[4] = f2bf(v1.x); tmp[5] = f2bf(v1.y); tmp[6] = f2bf(v1.z); tmp[7] = f2bf(v1.w);
        *(int4*)(w1p + (size_t)tid * 8) = *(int4*)tmp;
    } else {
        int tid = (bid - 320) * 256 + t;
        int kc = tid >> 11, rem = tid & 2047;
        int wave = rem >> 9, rem2 = rem & 511;
        int ks2 = rem2 >> 8, rem3 = rem2 & 255;
        int nt = rem3 >> 6, lane = rem3 & 63;
        int ln = lane & 15, quad = lane >> 4;
        const float* src = w2 + (size_t)(wave * 64 + nt * 16 + ln) * 1024 + kc * 64 + ks2 * 32 + quad * 8;
        float4 v0 = *(const float4*)src;
        float4 v1 = *(const float4*)(src + 4);
        alignas(16) u16 tmp[8];
        tmp[0] = f2bf(v0.x); tmp[1] = f2bf(v0.y); tmp[2] = f2bf(v0.z); tmp[3] = f2bf(v0.w);
        tmp[4] = f2bf(v1.x); tmp[5] = f2bf(v1.y); tmp[6] = f2bf(v1.z); tmp[7] = f2bf(v1.w);
        *(int4*)(w2p + (size_t)tid * 8) = *(int4*)tmp;
    }
}

// ---------------- K1: NCHW f32 -> NHWC bf16 transpose ----------------
__global__ __launch_bounds__(256) void k_transpose(const float* __restrict__ x, u16* __restrict__ xh) {
    __shared__ __align__(16) u16 tile[64][72];
    const int t = threadIdx.x;
    const int hw0 = blockIdx.x * 64;
    const int c0  = blockIdx.y * 64;
    const int b   = blockIdx.z;
    const int cl = t >> 2, wl = (t & 3) * 16;
    {
        int c = c0 + cl;
        const float* src = x + (size_t)(b * 256 + c) * 3136 + hw0 + wl;
        for (int q = 0; q < 4; q++) {
            float4 v = *(const float4*)(src + q * 4);
            u16* dst = &tile[cl][wl + q * 4];
            dst[0] = f2bf(v.x); dst[1] = f2bf(v.y); dst[2] = f2bf(v.z); dst[3] = f2bf(v.w);
        }
    }
    __syncthreads();
    const int hl = t >> 3, cl2 = (t & 7) * 8;
    for (int i = 0; i < 2; i++) {
        int hw = hl + i * 32;
        alignas(16) u16 tmp[8];
        for (int j = 0; j < 8; j++) tmp[j] = tile[cl2 + j][hw];
        u16* dst = xh + (size_t)(b * 3136 + hw0 + hw) * 256 + c0 + cl2;
        *(int4*)dst = *(int4*)tmp;
    }
}

// ---------------- K_ln: full LayerNorm, bf16 in -> bf16 out (materialized) ----------------
// grid 12544, block 256 (4 waves, 1 position/wave)
__global__ __launch_bounds__(256) void k_ln(const u16* __restrict__ in, u16* __restrict__ out,
                                            const float* __restrict__ g, const float* __restrict__ bta) {
    const int wave = threadIdx.x >> 6, lane = threadIdx.x & 63;
    const int p = blockIdx.x * 4 + wave;
    ushort4 v = *(const ushort4*)(in + (size_t)p * 256 + lane * 4);
    float f0 = bf2f(v.x), f1 = bf2f(v.y), f2 = bf2f(v.z), f3 = bf2f(v.w);
    float s = f0 + f1 + f2 + f3;
    float sq = f0 * f0 + f1 * f1 + f2 * f2 + f3 * f3;
    for (int o = 32; o >= 1; o >>= 1) { s += __shfl_xor(s, o, 64); sq += __shfl_xor(sq, o, 64); }
    float m = s * (1.f / 256.f);
    float var = sq * (1.f / 256.f) - m * m;
    float inv = rsqrtf(var + 1e-5f);
    float4 gv = *(const float4*)(g + lane * 4);
    float4 bv = *(const float4*)(bta + lane * 4);
    ushort4 o4;
    o4.x = f2bf((f0 - m) * inv * gv.x + bv.x);
    o4.y = f2bf((f1 - m) * inv * gv.y + bv.y);
    o4.z = f2bf((f2 - m) * inv * gv.z + bv.z);
    o4.w = f2bf((f3 - m) * inv * gv.w + bv.w);
    *(ushort4*)(out + (size_t)p * 256 + lane * 4) = o4;
}

// ---------------- K_qkv: qkv = xn @ wqkvb^T + [bq;bkv]  (pure-copy staging) ----------------
// grid 2352 1D, XCD-swizzled.
__global__ __launch_bounds__(256) void k_qkv(
    const u16* __restrict__ xn, const u16* __restrict__ Bw,
    const float* __restrict__ bq, const float* __restrict__ bkv,
    u16* __restrict__ out) {
    __shared__ __align__(16) u16 smem[17408];
    u16* As = smem;          // 128*32
    u16* Bs = smem + 4096;   // 128*32

    const int g = blockIdx.x;
    const int xcd = g & 7, idx = g >> 3;
    const int bm = xcd * 49 + idx / 6, bn = idx % 6;

    const int t = threadIdx.x;
    const int wave = t >> 6, lane = t & 63;
    const int wm = (wave >> 1) * 64, wn = (wave & 1) * 64;
    const int ln = lane & 15, quad = lane >> 4;

    f32x4 vzero = {0.f, 0.f, 0.f, 0.f};
    f32x4 acc[4][4];
    for (int i = 0; i < 4; i++) for (int j = 0; j < 4; j++) acc[i][j] = vzero;

    const int srow = t >> 2;
    const int scol = (t & 3) * 8;

    for (int k0 = 0; k0 < 256; k0 += 32) {
        for (int i = 0; i < 2; i++) {
            int r = srow + i * 64;
            *(int4*)&As[r * 32 + scol] = *(const int4*)(xn + (size_t)(bm * 128 + r) * 256 + k0 + scol);
            *(int4*)&Bs[r * 32 + scol] = *(const int4*)(Bw + (size_t)(bn * 128 + r) * 256 + k0 + scol);
        }
        __syncthreads();
        bf16x8 af[4], bfr[4];
        for (int mt = 0; mt < 4; mt++) af[mt] = *(const bf16x8*)&As[(wm + mt * 16 + ln) * 32 + quad * 8];
        for (int nt = 0; nt < 4; nt++) bfr[nt] = *(const bf16x8*)&Bs[(wn + nt * 16 + ln) * 32 + quad * 8];
        for (int mt = 0; mt < 4; mt++)
            for (int nt = 0; nt < 4; nt++)   // swapped: lane owns row (m), 4 consecutive cols
                acc[mt][nt] = __builtin_amdgcn_mfma_f32_16x16x32_bf16(bfr[nt], af[mt], acc[mt][nt], 0, 0, 0);
        __syncthreads();
    }

    u16* Cs = smem;  // [128][136]
    for (int nt = 0; nt < 4; nt++) {
        int gn0 = bn * 128 + wn + nt * 16 + quad * 4;
        f32x4 bv = (gn0 < 256) ? *(const f32x4*)(bq + gn0) : *(const f32x4*)(bkv + gn0 - 256);
        for (int mt = 0; mt < 4; mt++) {
            ushort4 pk;
            pk.x = f2bf(acc[mt][nt][0] + bv[0]);
            pk.y = f2bf(acc[mt][nt][1] + bv[1]);
            pk.z = f2bf(acc[mt][nt][2] + bv[2]);
            pk.w = f2bf(acc[mt][nt][3] + bv[3]);
            *(ushort4*)&Cs[(wm + mt * 16 + ln) * 136 + wn + nt * 16 + quad * 4] = pk;
        }
    }
    __syncthreads();
    const int row = t >> 4, col = (t & 15) * 8;
    for (int pass = 0; pass < 8; pass++) {
        int rr = pass * 16 + row;
        int4 v = *(int4*)&Cs[rr * 136 + col];
        *(int4*)(out + (size_t)(bm * 128 + rr) * 768 + bn * 128 + col) = v;
    }
}

// ---------------- K_mlp: fused out = x2 + g2*(gelu(xn@w1^T+b1)@w2^T+b2), NCHW f32 ----------------
// grid 784 XCD-swizzled; block = 64 positions. Weights read via fragment-ordered
// coalesced loads (w1p/w2p). Hs double-buffered -> 1 barrier/chunk.
__global__ __launch_bounds__(256) void k_mlp(
    const u16* __restrict__ xn, const u16* __restrict__ x2,
    const u16* __restrict__ w1p, const float* __restrict__ b1,
    const u16* __restrict__ w2p, const float* __restrict__ b2,
    const float* __restrict__ g2v, float* __restrict__ outT) {
    __shared__ __align__(16) u16 smem[16896 + 2 * 4608];  // As 64x264, Hs[2] 64x72
    u16* As = smem;

    const int g = blockIdx.x;
    const int bm = (g & 7) * 98 + (g >> 3);

    const int t = threadIdx.x;
    const int wave = t >> 6, lane = t & 63;
    const int ln = lane & 15, quad = lane >> 4;
    const int wn16 = wave * 16, wn64 = wave * 64;

    f32x4 vzero = {0.f, 0.f, 0.f, 0.f};
    f32x4 acc[4][4];  // [mt][nt]: n = wn64+nt*16+ln, m = mt*16+quad*4+r
    for (int i = 0; i < 4; i++) for (int j = 0; j < 4; j++) acc[i][j] = vzero;

    // stage A tile (pure copy, already LN'd)
    {
        const int srow = t >> 2, scb = (t & 3) * 8;
        for (int c = 0; c < 8; c++) {
            int col = scb + c * 32;
            *(int4*)&As[srow * 264 + col] = *(const int4*)(xn + (size_t)(bm * 64 + srow) * 256 + col);
        }
    }
    __syncthreads();

    for (int kc = 0; kc < 16; kc++) {
        u16* hs = smem + 16896 + (kc & 1) * 4608;  // double-buffered H chunk
        // ---- up: H chunk 64m x 64n; wave owns 16-wide n-slice. Coalesced frag loads. ----
        f32x4 up[4];
        for (int i = 0; i < 4; i++) up[i] = vzero;
        bf16x8 w1f[8];
        {
            const u16* base = w1p + (size_t)(kc * 2048 + wave * 512) * 8 + lane * 8;
            for (int ks = 0; ks < 8; ks++) w1f[ks] = *(const bf16x8*)(base + ks * 512);
        }
        for (int ks = 0; ks < 8; ks++)
            for (int mt = 0; mt < 4; mt++) {
                bf16x8 af = *(const bf16x8*)&As[(mt * 16 + ln) * 264 + ks * 32 + quad * 8];
                up[mt] = __builtin_amdgcn_mfma_f32_16x16x32_bf16(af, w1f[ks], up[mt], 0, 0, 0);
            }
        // gelu (sigmoid form; downstream scaled by gamma2~1e-6) -> hs
        float bv = b1[kc * 64 + wn16 + ln];
        for (int mt = 0; mt < 4; mt++)
            for (int r = 0; r < 4; r++) {
                float v = up[mt][r] + bv;
                float s = 1.f / (1.f + __expf(-1.702f * v));
                hs[(mt * 16 + quad * 4 + r) * 72 + wn16 + ln] = f2bf(v * s);
            }
        __syncthreads();
        // ---- down: acc += H @ W2c^T; coalesced w2 frag loads. ----
        {
            const u16* base2 = w2p + (size_t)(kc * 2048 + wave * 512) * 8 + lane * 8;
            for (int ks2 = 0; ks2 < 2; ks2++) {
                bf16x8 hf[4];
                for (int mt = 0; mt < 4; mt++)
                    hf[mt] = *(const bf16x8*)&hs[(mt * 16 + ln) * 72 + ks2 * 32 + quad * 8];
                for (int nt = 0; nt < 4; nt++) {
                    bf16x8 w2f = *(const bf16x8*)(base2 + (ks2 * 256 + nt * 64) * 8);
                    for (int mt = 0; mt < 4; mt++)
                        acc[mt][nt] = __builtin_amdgcn_mfma_f32_16x16x32_bf16(hf[mt], w2f, acc[mt][nt], 0, 0, 0);
                }
            }
        }
        // no trailing barrier: next chunk writes the other H buffer
    }

    // epilogue: lane owns channel gn, 4 consecutive positions -> float4 NCHW store
    const int b = bm / 49;
    for (int nt = 0; nt < 4; nt++) {
        int gn = wn64 + nt * 16 + ln;
        float bs = b2[gn], g2 = g2v[gn];
        for (int mt = 0; mt < 4; mt++) {
            int gm0 = bm * 64 + mt * 16 + quad * 4;
            int hw0 = gm0 - b * 3136;
            f32x4 res;
            for (int r = 0; r < 4; r++)
                res[r] = bf2f(x2[(size_t)(gm0 + r) * 256 + gn]) + g2 * (acc[mt][nt][r] + bs);
            *(f32x4*)(outT + (size_t)(b * 256 + gn) * 3136 + hw0) = res;
        }
    }
}

// ---------------- K_attn: halo attention + LayerScale residual ----------------
__global__ __launch_bounds__(256) void k_attn(
    const u16* __restrict__ qkv, const float* __restrict__ bias,
    const u16* __restrict__ xh, const float* __restrict__ gamma1,
    u16* __restrict__ x2) {
    __shared__ __align__(16) u16 Kl[208 * 40];
    __shared__ __align__(16) u16 Vt[32 * 232];
    __shared__ __align__(16) u16 Pl[4][16 * 232];

    const int t = threadIdx.x;
    const int blk = blockIdx.x, head = blockIdx.y, b = blockIdx.z;
    const int bh = blk / 7, bw = blk - bh * 7;
    const int wave = t >> 6, lane = t & 63;
    const int ln = lane & 15, quad = lane >> 4;

    {
        int4 z = {0, 0, 0, 0};
        for (int i = t; i < (32 * 232) / 8; i += 256) ((int4*)Vt)[i] = z;
        for (int i = t; i < (4 * 16 * 232) / 8; i += 256) ((int4*)&Pl[0][0])[i] = z;
    }
    __syncthreads();

    for (int cid = t; cid < 208 * 8; cid += 256) {
        int pos = cid >> 3, part = cid & 7;
        int i = pos / 14, j = pos - i * 14;
        int gh = bh * 8 - 3 + i, gw = bw * 8 - 3 + j;
        bool valid = (pos < 196) && ((unsigned)gh < 56u) && ((unsigned)gw < 56u);
        int d0 = (part & 3) * 8;
        int4 v = {0, 0, 0, 0};
        if (valid) {
            size_t p = (size_t)(b * 56 + gh) * 56 + gw;
            v = *(const int4*)(qkv + p * 768 + 256 + head * 64 + ((part & 4) ? 32 : 0) + d0);
        }
        if (!(part & 4)) {
            *(int4*)&Kl[pos * 40 + d0] = v;
        } else {
            alignas(16) u16 tmp[8];
            *(int4*)tmp = v;
            for (int jj = 0; jj < 8; jj++) Vt[(d0 + jj) * 232 + pos] = tmp[jj];
        }
    }
    __syncthreads();

    const int qrow = wave * 16 + ln;
    const int qh = bh * 8 + (qrow >> 3), qw = bw * 8 + (qrow & 7);
    const size_t qp = (size_t)(b * 56 + qh) * 56 + qw;
    bf16x8 qf = *(const bf16x8*)(qkv + qp * 768 + head * 32 + quad * 8);

    f32x4 vzero = {0.f, 0.f, 0.f, 0.f};
    float sv[13][4];
    float mx[4] = {-1e30f, -1e30f, -1e30f, -1e30f};
    const float scale = 0.17677669529663687f;
    for (int nt = 0; nt < 13; nt++) {
        bf16x8 kf = *(const bf16x8*)&Kl[(nt * 16 + ln) * 40 + quad * 8];
        f32x4 s = __builtin_amdgcn_mfma_f32_16x16x32_bf16(qf, kf, vzero, 0, 0, 0);
        int kk = nt * 16 + ln;
        bool kvalid = kk < 196;
        for (int r = 0; r < 4; r++) {
            int qq = wave * 16 + quad * 4 + r;
            float val = kvalid ? (s[r] * scale + bias[(size_t)(head * 64 + qq) * 196 + kk]) : -1e30f;
            sv[nt][r] = val;
            mx[r] = fmaxf(mx[r], val);
        }
    }
    for (int o = 1; o < 16; o <<= 1)
        for (int r = 0; r < 4; r++) mx[r] = fmaxf(mx[r], __shfl_xor(mx[r], o, 16));
    float sum[4] = {0.f, 0.f, 0.f, 0.f};
    for (int nt = 0; nt < 13; nt++)
        for (int r = 0; r < 4; r++) {
            float e = __expf(sv[nt][r] - mx[r]);
            sv[nt][r] = e;
            sum[r] += e;
        }
    for (int o = 1; o < 16; o <<= 1)
        for (int r = 0; r < 4; r++) sum[r] += __shfl_xor(sum[r], o, 16);
    float rinv[4];
    for (int r = 0; r < 4; r++) rinv[r] = 1.f / sum[r];

    u16* plw = &Pl[wave][0];
    for (int nt = 0; nt < 13; nt++)
        for (int r = 0; r < 4; r++)
            plw[(quad * 4 + r) * 232 + nt * 16 + ln] = f2bf(sv[nt][r]);
    __syncthreads();

    f32x4 o_acc[2];
    o_acc[0] = vzero; o_acc[1] = vzero;
    for (int kc = 0; kc < 7; kc++) {
        bf16x8 pf = *(const bf16x8*)&plw[ln * 232 + kc * 32 + quad * 8];
        for (int n2 = 0; n2 < 2; n2++) {
            bf16x8 vf = *(const bf16x8*)&Vt[(n2 * 16 + ln) * 232 + kc * 32 + quad * 8];
            o_acc[n2] = __builtin_amdgcn_mfma_f32_16x16x32_bf16(pf, vf, o_acc[n2], 0, 0, 0);
        }
    }

    for (int n2 = 0; n2 < 2; n2++) {
        int c = head * 32 + n2 * 16 + ln;
        float g1 = gamma1[c];
        for (int r = 0; r < 4; r++) {
            int q = wave * 16 + quad * 4 + r;
            int hh = bh * 8 + (q >> 3), ww = bw * 8 + (q & 7);
            size_t p = (size_t)(b * 56 + hh) * 56 + ww;
            float a = o_acc[n2][r] * rinv[r];
            x2[p * 256 + c] = f2bf(bf2f(xh[p * 256 + c]) + g1 * a);
        }
    }
}

extern "C" void kernel_launch(void* const* d_in, const int* in_sizes, int n_in,
                              void* d_out, int out_size, void* d_ws, size_t ws_size,
                              hipStream_t stream) {
    const float* x      = (const float*)d_in[0];
    const float* ln1_g  = (const float*)d_in[1];
    const float* ln1_b  = (const float*)d_in[2];
    const float* wq     = (const float*)d_in[3];
    const float* bq     = (const float*)d_in[4];
    const float* wkv    = (const float*)d_in[5];
    const float* bkv    = (const float*)d_in[6];
    const float* bias   = (const float*)d_in[7];
    const float* gamma1 = (const float*)d_in[8];
    const float* ln2_g  = (const float*)d_in[9];
    const float* ln2_b  = (const float*)d_in[10];
    const float* w1     = (const float*)d_in[11];
    const float* b1     = (const float*)d_in[12];
    const float* w2     = (const float*)d_in[13];
    const float* b2     = (const float*)d_in[14];
    const float* gamma2 = (const float*)d_in[15];

    char* ws = (char*)d_ws;
    u16* qkv   = (u16*)ws;                      // 77,070,336 B
    u16* xh    = (u16*)(ws + 77070336);         // 25,690,112 B  (also reused as xn2)
    u16* x2    = (u16*)(ws + 102760448);        // 25,690,112 B  (also reused as xn1)
    u16* wqkvb = (u16*)(ws + 128450560);        // 393,216 B
    u16* w1p   = (u16*)(ws + 128843776);        // 524,288 B
    u16* w2p   = (u16*)(ws + 129368064);        // 524,288 B
    u16* xn1   = x2;   // LN1 output; dead before k_attn writes x2
    u16* xn2   = xh;   // LN2 output; xh dead after k_attn

    k_prep<<<dim3(448), 256, 0, stream>>>(wq, wkv, w1, w2, wqkvb, w1p, w2p);
    k_transpose<<<dim3(49, 4, 16), 256, 0, stream>>>(x, xh);
    k_ln<<<dim3(12544), 256, 0, stream>>>(xh, xn1, ln1_g, ln1_b);
    k_qkv<<<dim3(2352), 256, 0, stream>>>(xn1, wqkvb, bq, bkv, qkv);
    k_attn<<<dim3(49, 8, 16), 256, 0, stream>>>(qkv, bias, xh, gamma1, x2);
    k_ln<<<dim3(12544), 256, 0, stream>>>(x2, xn2, ln2_g, ln2_b);
    k_mlp<<<dim3(784), 256, 0, stream>>>(xn2, x2, w1p, b1, w2p, b2, gamma2, (float*)d_out);
}